// Round 1
// baseline (934.142 us; speedup 1.0000x reference)
//
#include <hip/hip_runtime.h>
#include <math.h>

#define NTOK 16384
#define DDIM 512
#define MDIM 1024
#define NEXP 8

typedef __attribute__((ext_vector_type(8))) short short8;
typedef __attribute__((ext_vector_type(4))) float floatx4;

__device__ inline unsigned short f2bf(float f){
  union { float f; unsigned int u; } v; v.f = f;
  unsigned int u = v.u;
  u += ((u >> 16) & 1u) + 0x7fffu;   // round-to-nearest-even
  return (unsigned short)(u >> 16);
}

__device__ inline float gelu_exact(float x){
  return 0.5f * x * (1.0f + erff(x * 0.70710678118654752440f));
}

// ---------------- small setup kernels ----------------

__global__ void init_small_kernel(int* counts, float* imp){
  int t = threadIdx.x;
  if (t < NEXP){ counts[t] = 0; imp[t] = 0.0f; }
}

__global__ void conv_x_kernel(const float* __restrict__ x,
                              unsigned short* __restrict__ xb, int n4){
  int stride = gridDim.x * blockDim.x;
  for (int i = blockIdx.x * blockDim.x + threadIdx.x; i < n4; i += stride){
    float4 v = ((const float4*)x)[i];
    ushort4 o;
    o.x = f2bf(v.x); o.y = f2bf(v.y); o.z = f2bf(v.z); o.w = f2bf(v.w);
    ((ushort4*)xb)[i] = o;
  }
}

// out[e][c][r] = bf16(in[e][r][c]); per-expert matrix is R x C
__global__ void transpose_conv_kernel(const float* __restrict__ in,
                                      unsigned short* __restrict__ out,
                                      int R, int C){
  __shared__ float tile[32][33];
  int e  = blockIdx.z;
  int c0 = blockIdx.x << 5;
  int r0 = blockIdx.y << 5;
  const float* src = in + (size_t)e * R * C;
  unsigned short* dst = out + (size_t)e * R * C;
  int tc = threadIdx.x;   // 0..31
  int tr = threadIdx.y;   // 0..7
  #pragma unroll
  for (int i = 0; i < 32; i += 8)
    tile[tr + i][tc] = src[(size_t)(r0 + tr + i) * C + c0 + tc];
  __syncthreads();
  #pragma unroll
  for (int i = 0; i < 32; i += 8)
    dst[(size_t)(c0 + tr + i) * R + r0 + tc] = f2bf(tile[tc][tr + i]);
}

__global__ void zero_y_kernel(float* __restrict__ y, int n4){
  int stride = gridDim.x * blockDim.x;
  float4 z = {0.f, 0.f, 0.f, 0.f};
  for (int i = blockIdx.x * blockDim.x + threadIdx.x; i < n4; i += stride)
    ((float4*)y)[i] = z;
}

// ---------------- gating (fp64 logits for exact top-2 vs reference) ----------------

__global__ void gating_kernel(const float* __restrict__ x,
                              const float* __restrict__ wg,
                              int* __restrict__ tok_e, float* __restrict__ tok_g,
                              int* __restrict__ counts, float* __restrict__ imp){
  int wave = threadIdx.x >> 6;
  int lane = threadIdx.x & 63;
  int n = blockIdx.x * 4 + wave;

  const float4* xp = (const float4*)(x + (size_t)n * DDIM + lane * 8);
  float4 a = xp[0], b = xp[1];
  float xv[8] = {a.x, a.y, a.z, a.w, b.x, b.y, b.z, b.w};

  double acc[NEXP];
  #pragma unroll
  for (int e = 0; e < NEXP; e++) acc[e] = 0.0;
  #pragma unroll
  for (int j = 0; j < 8; j++){
    const float* wr = wg + (size_t)(lane * 8 + j) * NEXP;
    #pragma unroll
    for (int e = 0; e < NEXP; e++) acc[e] += (double)xv[j] * (double)wr[e];
  }
  #pragma unroll
  for (int off = 32; off >= 1; off >>= 1){
    #pragma unroll
    for (int e = 0; e < NEXP; e++) acc[e] += __shfl_xor(acc[e], off);
  }
  if (lane == 0){
    int i0 = -1, i1 = -1;
    double l0 = -1e300, l1 = -1e300;
    #pragma unroll
    for (int e = 0; e < NEXP; e++){
      double v = acc[e];
      if (v > l0){ l1 = l0; i1 = i0; l0 = v; i0 = e; }
      else if (v > l1){ l1 = v; i1 = e; }
    }
    float ex = expf((float)(l1 - l0));
    float g0 = 1.0f / (1.0f + ex);
    float g1 = ex / (1.0f + ex);
    tok_e[n * 2]     = i0; tok_e[n * 2 + 1] = i1;
    tok_g[n * 2]     = g0; tok_g[n * 2 + 1] = g1;
    atomicAdd(&counts[i0], 1); atomicAdd(&counts[i1], 1);
    atomicAdd(&imp[i0], g0);   atomicAdd(&imp[i1], g1);
  }
}

__global__ void loss_scan_kernel(const int* __restrict__ counts,
                                 const float* __restrict__ imp,
                                 int* __restrict__ offsets, int* __restrict__ cursor,
                                 float* __restrict__ out_loss){
  int off = 0;
  double si = 0, si2 = 0, sl = 0, sl2 = 0;
  for (int e = 0; e < NEXP; e++){
    offsets[e] = off; cursor[e] = off; off += counts[e];
    double im = (double)imp[e];
    double ld = (double)counts[e];
    si += im; si2 += im * im;
    sl += ld; sl2 += ld * ld;
  }
  offsets[NEXP] = off;
  double mi = si / 8.0, ml = sl / 8.0;
  double vi = (si2 - 8.0 * mi * mi) / 7.0;
  double vl = (sl2 - 8.0 * ml * ml) / 7.0;
  double loss = 0.01 * (vi / (mi * mi + 1e-10) + vl / (ml * ml + 1e-10));
  *out_loss = (float)loss;
}

__global__ void scatter_kernel(const int* __restrict__ tok_e,
                               const float* __restrict__ tok_g,
                               int* __restrict__ cursor,
                               int* __restrict__ btok, float* __restrict__ bgate){
  int n = blockIdx.x * blockDim.x + threadIdx.x;
  if (n >= NTOK) return;
  #pragma unroll
  for (int k = 0; k < 2; k++){
    int e = tok_e[n * 2 + k];
    int slot = atomicAdd(&cursor[e], 1);
    btok[slot] = n;
    bgate[slot] = tok_g[n * 2 + k];
  }
}

// ---------------- expert GEMMs: 128x128 tile, BK=32, mfma 16x16x32 bf16 ----------------
// A and B^T both stored [row][K] contiguous; identical fragment load pattern.

__global__ __launch_bounds__(256)
void gemm1_kernel(const unsigned short* __restrict__ xb,
                  const unsigned short* __restrict__ w1t,   // [E][M][D]
                  const float* __restrict__ b1,             // [E][M]
                  const int* __restrict__ offsets,
                  const int* __restrict__ btok,
                  unsigned short* __restrict__ H){          // [slot][M]
  int blk = blockIdx.x;
  int e  = blk >> 10;          // 8 col-tiles * 128 row-tiles
  int ct = (blk >> 7) & 7;
  int rt = blk & 127;
  int off = offsets[e];
  int cnt = offsets[e + 1] - off;
  int r0 = rt << 7;
  if (r0 >= cnt) return;

  __shared__ unsigned short As[128 * 32];
  __shared__ unsigned short Bs[128 * 32];

  int t = threadIdx.x;
  int srow = t >> 2;           // 0..63
  int scol = (t & 3) << 3;     // 0,8,16,24

  int ra0 = r0 + srow;        if (ra0 >= cnt) ra0 = cnt - 1;
  int ra1 = r0 + 64 + srow;   if (ra1 >= cnt) ra1 = cnt - 1;
  const unsigned short* aptr0 = xb + (size_t)btok[off + ra0] * DDIM + scol;
  const unsigned short* aptr1 = xb + (size_t)btok[off + ra1] * DDIM + scol;
  const unsigned short* bptr0 = w1t + ((size_t)e * MDIM + (ct << 7) + srow) * DDIM + scol;
  const unsigned short* bptr1 = bptr0 + (size_t)64 * DDIM;

  unsigned short* As0 = &As[srow * 32 + scol];
  unsigned short* As1 = &As[(srow + 64) * 32 + scol];
  unsigned short* Bs0 = &Bs[srow * 32 + scol];
  unsigned short* Bs1 = &Bs[(srow + 64) * 32 + scol];

  int lane = t & 63;
  int wv = t >> 6;
  int wr = (wv >> 1) << 6;
  int wc = (wv & 1) << 6;
  int lm = lane & 15;
  int lq = lane >> 4;

  const unsigned short* Ar[4];
  const unsigned short* Br[4];
  #pragma unroll
  for (int i = 0; i < 4; i++){
    Ar[i] = &As[(wr + i * 16 + lm) * 32 + lq * 8];
    Br[i] = &Bs[(wc + i * 16 + lm) * 32 + lq * 8];
  }

  floatx4 acc[4][4] = {};
  for (int k0 = 0; k0 < DDIM; k0 += 32){
    *(short8*)As0 = *(const short8*)(aptr0 + k0);
    *(short8*)As1 = *(const short8*)(aptr1 + k0);
    *(short8*)Bs0 = *(const short8*)(bptr0 + k0);
    *(short8*)Bs1 = *(const short8*)(bptr1 + k0);
    __syncthreads();
    short8 af[4], bf[4];
    #pragma unroll
    for (int i = 0; i < 4; i++) af[i] = *(const short8*)Ar[i];
    #pragma unroll
    for (int j = 0; j < 4; j++) bf[j] = *(const short8*)Br[j];
    #pragma unroll
    for (int i = 0; i < 4; i++)
      #pragma unroll
      for (int j = 0; j < 4; j++)
        acc[i][j] = __builtin_amdgcn_mfma_f32_16x16x32_bf16(af[i], bf[j], acc[i][j], 0, 0, 0);
    __syncthreads();
  }

  const float* bias = b1 + e * MDIM + (ct << 7);
  #pragma unroll
  for (int i = 0; i < 4; i++){
    int rbase = wr + i * 16 + lq * 4;
    #pragma unroll
    for (int j = 0; j < 4; j++){
      int cc = wc + j * 16 + lm;
      float bv = bias[cc];
      #pragma unroll
      for (int r = 0; r < 4; r++){
        int row = r0 + rbase + r;
        if (row < cnt){
          float v = acc[i][j][r] + bv;
          H[(size_t)(off + row) * MDIM + (ct << 7) + cc] = f2bf(gelu_exact(v));
        }
      }
    }
  }
}

__global__ __launch_bounds__(256)
void gemm2_kernel(const unsigned short* __restrict__ H,    // [slot][M]
                  const unsigned short* __restrict__ w2t,  // [E][D][M]
                  const float* __restrict__ b2,            // [E][D]
                  const int* __restrict__ offsets,
                  const int* __restrict__ btok,
                  const float* __restrict__ bgate,
                  float* __restrict__ y){
  int blk = blockIdx.x;
  int e  = blk >> 9;           // 4 col-tiles * 128 row-tiles
  int ct = (blk >> 7) & 3;
  int rt = blk & 127;
  int off = offsets[e];
  int cnt = offsets[e + 1] - off;
  int r0 = rt << 7;
  if (r0 >= cnt) return;

  __shared__ unsigned short As[128 * 32];
  __shared__ unsigned short Bs[128 * 32];

  int t = threadIdx.x;
  int srow = t >> 2;
  int scol = (t & 3) << 3;

  int ra0 = r0 + srow;        if (ra0 >= cnt) ra0 = cnt - 1;
  int ra1 = r0 + 64 + srow;   if (ra1 >= cnt) ra1 = cnt - 1;
  const unsigned short* aptr0 = H + (size_t)(off + ra0) * MDIM + scol;
  const unsigned short* aptr1 = H + (size_t)(off + ra1) * MDIM + scol;
  const unsigned short* bptr0 = w2t + ((size_t)e * DDIM + (ct << 7) + srow) * MDIM + scol;
  const unsigned short* bptr1 = bptr0 + (size_t)64 * MDIM;

  unsigned short* As0 = &As[srow * 32 + scol];
  unsigned short* As1 = &As[(srow + 64) * 32 + scol];
  unsigned short* Bs0 = &Bs[srow * 32 + scol];
  unsigned short* Bs1 = &Bs[(srow + 64) * 32 + scol];

  int lane = t & 63;
  int wv = t >> 6;
  int wr = (wv >> 1) << 6;
  int wc = (wv & 1) << 6;
  int lm = lane & 15;
  int lq = lane >> 4;

  const unsigned short* Ar[4];
  const unsigned short* Br[4];
  #pragma unroll
  for (int i = 0; i < 4; i++){
    Ar[i] = &As[(wr + i * 16 + lm) * 32 + lq * 8];
    Br[i] = &Bs[(wc + i * 16 + lm) * 32 + lq * 8];
  }

  floatx4 acc[4][4] = {};
  for (int k0 = 0; k0 < MDIM; k0 += 32){
    *(short8*)As0 = *(const short8*)(aptr0 + k0);
    *(short8*)As1 = *(const short8*)(aptr1 + k0);
    *(short8*)Bs0 = *(const short8*)(bptr0 + k0);
    *(short8*)Bs1 = *(const short8*)(bptr1 + k0);
    __syncthreads();
    short8 af[4], bf[4];
    #pragma unroll
    for (int i = 0; i < 4; i++) af[i] = *(const short8*)Ar[i];
    #pragma unroll
    for (int j = 0; j < 4; j++) bf[j] = *(const short8*)Br[j];
    #pragma unroll
    for (int i = 0; i < 4; i++)
      #pragma unroll
      for (int j = 0; j < 4; j++)
        acc[i][j] = __builtin_amdgcn_mfma_f32_16x16x32_bf16(af[i], bf[j], acc[i][j], 0, 0, 0);
    __syncthreads();
  }

  const float* bias = b2 + e * DDIM + (ct << 7);
  #pragma unroll
  for (int i = 0; i < 4; i++){
    int rbase = wr + i * 16 + lq * 4;
    #pragma unroll
    for (int j = 0; j < 4; j++){
      int cc = wc + j * 16 + lm;
      float bv = bias[cc];
      #pragma unroll
      for (int r = 0; r < 4; r++){
        int row = r0 + rbase + r;
        if (row < cnt){
          int tok = btok[off + row];
          float g = bgate[off + row];
          atomicAdd(&y[(size_t)tok * DDIM + (ct << 7) + cc], g * (acc[i][j][r] + bv));
        }
      }
    }
  }
}

// ---------------- launch ----------------

extern "C" void kernel_launch(void* const* d_in, const int* in_sizes, int n_in,
                              void* d_out, int out_size, void* d_ws, size_t ws_size,
                              hipStream_t stream){
  const float* x  = (const float*)d_in[0];
  const float* wg = (const float*)d_in[1];
  const float* W1 = (const float*)d_in[2];
  const float* b1 = (const float*)d_in[3];
  const float* W2 = (const float*)d_in[4];
  const float* b2 = (const float*)d_in[5];
  float* y = (float*)d_out;

  char* ws = (char*)d_ws;
  size_t o = 0;
  auto alloc = [&](size_t bytes)->char*{
    char* p = ws + o;
    o += (bytes + 255) & ~(size_t)255;
    return p;
  };
  unsigned short* xb   = (unsigned short*)alloc((size_t)NTOK * DDIM * 2);
  unsigned short* w1t  = (unsigned short*)alloc((size_t)NEXP * MDIM * DDIM * 2);
  unsigned short* w2t  = (unsigned short*)alloc((size_t)NEXP * DDIM * MDIM * 2);
  unsigned short* H    = (unsigned short*)alloc((size_t)NTOK * 2 * MDIM * 2);
  int*   btok    = (int*)  alloc((size_t)NTOK * 2 * 4);
  float* bgate   = (float*)alloc((size_t)NTOK * 2 * 4);
  int*   tok_e   = (int*)  alloc((size_t)NTOK * 2 * 4);
  float* tok_g   = (float*)alloc((size_t)NTOK * 2 * 4);
  int*   counts  = (int*)  alloc(64);
  float* imp     = (float*)alloc(64);
  int*   offsets = (int*)  alloc(64);
  int*   cursor  = (int*)  alloc(64);

  hipLaunchKernelGGL(init_small_kernel, dim3(1), dim3(64), 0, stream, counts, imp);
  hipLaunchKernelGGL(conv_x_kernel, dim3(2048), dim3(256), 0, stream,
                     x, xb, NTOK * DDIM / 4);
  hipLaunchKernelGGL(transpose_conv_kernel, dim3(MDIM / 32, DDIM / 32, NEXP), dim3(32, 8), 0, stream,
                     W1, w1t, DDIM, MDIM);
  hipLaunchKernelGGL(transpose_conv_kernel, dim3(DDIM / 32, MDIM / 32, NEXP), dim3(32, 8), 0, stream,
                     W2, w2t, MDIM, DDIM);
  hipLaunchKernelGGL(gating_kernel, dim3(NTOK / 4), dim3(256), 0, stream,
                     x, wg, tok_e, tok_g, counts, imp);
  hipLaunchKernelGGL(loss_scan_kernel, dim3(1), dim3(1), 0, stream,
                     counts, imp, offsets, cursor, y + (size_t)NTOK * DDIM);
  hipLaunchKernelGGL(scatter_kernel, dim3(NTOK / 256), dim3(256), 0, stream,
                     tok_e, tok_g, cursor, btok, bgate);
  hipLaunchKernelGGL(zero_y_kernel, dim3(2048), dim3(256), 0, stream,
                     y, NTOK * DDIM / 4);
  hipLaunchKernelGGL(gemm1_kernel, dim3(NEXP * 8 * 128), dim3(256), 0, stream,
                     xb, w1t, b1, offsets, btok, H);
  hipLaunchKernelGGL(gemm2_kernel, dim3(NEXP * 4 * 128), dim3(256), 0, stream,
                     H, w2t, b2, offsets, btok, bgate, y);
}

// Round 2
// 405.821 us; speedup vs baseline: 2.3019x; 2.3019x over previous
//
#include <hip/hip_runtime.h>
#include <math.h>

#define NTOK 16384
#define DDIM 512
#define MDIM 1024
#define NEXP 8

typedef __attribute__((ext_vector_type(8))) short short8;
typedef __attribute__((ext_vector_type(4))) float floatx4;

__device__ inline unsigned short f2bf(float f){
  union { float f; unsigned int u; } v; v.f = f;
  unsigned int u = v.u;
  u += ((u >> 16) & 1u) + 0x7fffu;   // round-to-nearest-even
  return (unsigned short)(u >> 16);
}

__device__ inline float gelu_exact(float x){
  return 0.5f * x * (1.0f + erff(x * 0.70710678118654752440f));
}

// ---------------- small setup kernels ----------------

__global__ void init_small_kernel(int* counts, float* imp){
  int t = threadIdx.x;
  if (t < NEXP){ counts[t] = 0; imp[t] = 0.0f; }
}

// out[e][c][r] = bf16(in[e][r][c]); per-expert matrix is R x C
__global__ void transpose_conv_kernel(const float* __restrict__ in,
                                      unsigned short* __restrict__ out,
                                      int R, int C){
  __shared__ float tile[32][33];
  int e  = blockIdx.z;
  int c0 = blockIdx.x << 5;
  int r0 = blockIdx.y << 5;
  const float* src = in + (size_t)e * R * C;
  unsigned short* dst = out + (size_t)e * R * C;
  int tc = threadIdx.x;   // 0..31
  int tr = threadIdx.y;   // 0..7
  #pragma unroll
  for (int i = 0; i < 32; i += 8)
    tile[tr + i][tc] = src[(size_t)(r0 + tr + i) * C + c0 + tc];
  __syncthreads();
  #pragma unroll
  for (int i = 0; i < 32; i += 8)
    dst[(size_t)(c0 + tr + i) * R + r0 + tc] = f2bf(tile[tc][tr + i]);
}

__global__ void zero_y_kernel(float* __restrict__ y, int n4){
  int stride = gridDim.x * blockDim.x;
  float4 z = {0.f, 0.f, 0.f, 0.f};
  for (int i = blockIdx.x * blockDim.x + threadIdx.x; i < n4; i += stride)
    ((float4*)y)[i] = z;
}

// ---------------- fused gating + x->bf16 conversion ----------------
// 256 blocks x 256 threads; block handles 64 tokens (4 waves x 16 iter).
// fp64 logits for exact top-2 vs reference; counts/imp accumulated in LDS,
// flushed with 16 global atomics per block (was: 4 per token => contention).

__global__ __launch_bounds__(256)
void gating_kernel(const float* __restrict__ x,
                   const float* __restrict__ wg,
                   unsigned short* __restrict__ xb,
                   int* __restrict__ tok_e, float* __restrict__ tok_g,
                   int* __restrict__ counts, float* __restrict__ imp){
  __shared__ int   lcnt[NEXP];
  __shared__ float limp[NEXP];
  int t = threadIdx.x;
  if (t < NEXP){ lcnt[t] = 0; limp[t] = 0.0f; }
  __syncthreads();

  int wave = t >> 6;
  int lane = t & 63;

  for (int it = 0; it < 16; it++){
    int n = blockIdx.x * 64 + it * 4 + wave;

    const float4* xp = (const float4*)(x + (size_t)n * DDIM + lane * 8);
    float4 a = xp[0], b = xp[1];
    float xv[8] = {a.x, a.y, a.z, a.w, b.x, b.y, b.z, b.w};

    // write bf16 copy of x (coalesced 16B/lane)
    short8 xo;
    #pragma unroll
    for (int j = 0; j < 8; j++) xo[j] = (short)f2bf(xv[j]);
    *(short8*)(xb + (size_t)n * DDIM + lane * 8) = xo;

    double acc[NEXP];
    #pragma unroll
    for (int e = 0; e < NEXP; e++) acc[e] = 0.0;
    #pragma unroll
    for (int j = 0; j < 8; j++){
      const float* wr = wg + (size_t)(lane * 8 + j) * NEXP;
      #pragma unroll
      for (int e = 0; e < NEXP; e++) acc[e] += (double)xv[j] * (double)wr[e];
    }
    #pragma unroll
    for (int off = 32; off >= 1; off >>= 1){
      #pragma unroll
      for (int e = 0; e < NEXP; e++) acc[e] += __shfl_xor(acc[e], off);
    }
    if (lane == 0){
      int i0 = -1, i1 = -1;
      double l0 = -1e300, l1 = -1e300;
      #pragma unroll
      for (int e = 0; e < NEXP; e++){
        double v = acc[e];
        if (v > l0){ l1 = l0; i1 = i0; l0 = v; i0 = e; }
        else if (v > l1){ l1 = v; i1 = e; }
      }
      float ex = expf((float)(l1 - l0));
      float g0 = 1.0f / (1.0f + ex);
      float g1 = ex / (1.0f + ex);
      tok_e[n * 2]     = i0; tok_e[n * 2 + 1] = i1;
      tok_g[n * 2]     = g0; tok_g[n * 2 + 1] = g1;
      atomicAdd(&lcnt[i0], 1); atomicAdd(&lcnt[i1], 1);
      atomicAdd(&limp[i0], g0); atomicAdd(&limp[i1], g1);
    }
  }
  __syncthreads();
  if (t < NEXP){
    atomicAdd(&counts[t], lcnt[t]);
    atomicAdd(&imp[t], limp[t]);
  }
}

__global__ void loss_scan_kernel(const int* __restrict__ counts,
                                 const float* __restrict__ imp,
                                 int* __restrict__ offsets, int* __restrict__ cursor,
                                 float* __restrict__ out_loss){
  int off = 0;
  double si = 0, si2 = 0, sl = 0, sl2 = 0;
  for (int e = 0; e < NEXP; e++){
    offsets[e] = off; cursor[e] = off; off += counts[e];
    double im = (double)imp[e];
    double ld = (double)counts[e];
    si += im; si2 += im * im;
    sl += ld; sl2 += ld * ld;
  }
  offsets[NEXP] = off;
  double mi = si / 8.0, ml = sl / 8.0;
  double vi = (si2 - 8.0 * mi * mi) / 7.0;
  double vl = (sl2 - 8.0 * ml * ml) / 7.0;
  double loss = 0.01 * (vi / (mi * mi + 1e-10) + vl / (ml * ml + 1e-10));
  *out_loss = (float)loss;
}

// hierarchical scatter: LDS histogram -> 8 global atomics per block -> ranked write
__global__ __launch_bounds__(256)
void scatter_kernel(const int* __restrict__ tok_e,
                    const float* __restrict__ tok_g,
                    int* __restrict__ cursor,
                    int* __restrict__ btok, float* __restrict__ bgate){
  __shared__ int lcnt[NEXP];
  __shared__ int lbase[NEXP];
  int t = threadIdx.x;
  if (t < NEXP) lcnt[t] = 0;
  __syncthreads();

  int n = blockIdx.x * 256 + t;
  int e0 = tok_e[n * 2], e1 = tok_e[n * 2 + 1];
  float g0 = tok_g[n * 2], g1 = tok_g[n * 2 + 1];
  int r0 = atomicAdd(&lcnt[e0], 1);
  int r1 = atomicAdd(&lcnt[e1], 1);
  __syncthreads();
  if (t < NEXP) lbase[t] = atomicAdd(&cursor[t], lcnt[t]);
  __syncthreads();
  int s0 = lbase[e0] + r0;
  int s1 = lbase[e1] + r1;
  btok[s0] = n;  bgate[s0] = g0;
  btok[s1] = n;  bgate[s1] = g1;
}

// ---------------- expert GEMMs: 128x128 tile, BK=32, mfma 16x16x32 bf16 ----------------

__global__ __launch_bounds__(256)
void gemm1_kernel(const unsigned short* __restrict__ xb,
                  const unsigned short* __restrict__ w1t,   // [E][M][D]
                  const float* __restrict__ b1,             // [E][M]
                  const int* __restrict__ offsets,
                  const int* __restrict__ btok,
                  unsigned short* __restrict__ H){          // [slot][M]
  int blk = blockIdx.x;
  int e  = blk >> 10;          // 8 col-tiles * 128 row-tiles
  int ct = (blk >> 7) & 7;
  int rt = blk & 127;
  int off = offsets[e];
  int cnt = offsets[e + 1] - off;
  int r0 = rt << 7;
  if (r0 >= cnt) return;

  __shared__ unsigned short As[128 * 32];
  __shared__ unsigned short Bs[128 * 32];

  int t = threadIdx.x;
  int srow = t >> 2;           // 0..63
  int scol = (t & 3) << 3;     // 0,8,16,24

  int ra0 = r0 + srow;        if (ra0 >= cnt) ra0 = cnt - 1;
  int ra1 = r0 + 64 + srow;   if (ra1 >= cnt) ra1 = cnt - 1;
  const unsigned short* aptr0 = xb + (size_t)btok[off + ra0] * DDIM + scol;
  const unsigned short* aptr1 = xb + (size_t)btok[off + ra1] * DDIM + scol;
  const unsigned short* bptr0 = w1t + ((size_t)e * MDIM + (ct << 7) + srow) * DDIM + scol;
  const unsigned short* bptr1 = bptr0 + (size_t)64 * DDIM;

  unsigned short* As0 = &As[srow * 32 + scol];
  unsigned short* As1 = &As[(srow + 64) * 32 + scol];
  unsigned short* Bs0 = &Bs[srow * 32 + scol];
  unsigned short* Bs1 = &Bs[(srow + 64) * 32 + scol];

  int lane = t & 63;
  int wv = t >> 6;
  int wr = (wv >> 1) << 6;
  int wc = (wv & 1) << 6;
  int lm = lane & 15;
  int lq = lane >> 4;

  const unsigned short* Ar[4];
  const unsigned short* Br[4];
  #pragma unroll
  for (int i = 0; i < 4; i++){
    Ar[i] = &As[(wr + i * 16 + lm) * 32 + lq * 8];
    Br[i] = &Bs[(wc + i * 16 + lm) * 32 + lq * 8];
  }

  floatx4 acc[4][4] = {};
  for (int k0 = 0; k0 < DDIM; k0 += 32){
    *(short8*)As0 = *(const short8*)(aptr0 + k0);
    *(short8*)As1 = *(const short8*)(aptr1 + k0);
    *(short8*)Bs0 = *(const short8*)(bptr0 + k0);
    *(short8*)Bs1 = *(const short8*)(bptr1 + k0);
    __syncthreads();
    short8 af[4], bf[4];
    #pragma unroll
    for (int i = 0; i < 4; i++) af[i] = *(const short8*)Ar[i];
    #pragma unroll
    for (int j = 0; j < 4; j++) bf[j] = *(const short8*)Br[j];
    #pragma unroll
    for (int i = 0; i < 4; i++)
      #pragma unroll
      for (int j = 0; j < 4; j++)
        acc[i][j] = __builtin_amdgcn_mfma_f32_16x16x32_bf16(af[i], bf[j], acc[i][j], 0, 0, 0);
    __syncthreads();
  }

  const float* bias = b1 + e * MDIM + (ct << 7);
  #pragma unroll
  for (int i = 0; i < 4; i++){
    int rbase = wr + i * 16 + lq * 4;
    #pragma unroll
    for (int j = 0; j < 4; j++){
      int cc = wc + j * 16 + lm;
      float bv = bias[cc];
      #pragma unroll
      for (int r = 0; r < 4; r++){
        int row = r0 + rbase + r;
        if (row < cnt){
          float v = acc[i][j][r] + bv;
          H[(size_t)(off + row) * MDIM + (ct << 7) + cc] = f2bf(gelu_exact(v));
        }
      }
    }
  }
}

__global__ __launch_bounds__(256)
void gemm2_kernel(const unsigned short* __restrict__ H,    // [slot][M]
                  const unsigned short* __restrict__ w2t,  // [E][D][M]
                  const float* __restrict__ b2,            // [E][D]
                  const int* __restrict__ offsets,
                  const int* __restrict__ btok,
                  const float* __restrict__ bgate,
                  float* __restrict__ y){
  int blk = blockIdx.x;
  int e  = blk >> 9;           // 4 col-tiles * 128 row-tiles
  int ct = (blk >> 7) & 3;
  int rt = blk & 127;
  int off = offsets[e];
  int cnt = offsets[e + 1] - off;
  int r0 = rt << 7;
  if (r0 >= cnt) return;

  __shared__ unsigned short As[128 * 32];
  __shared__ unsigned short Bs[128 * 32];

  int t = threadIdx.x;
  int srow = t >> 2;
  int scol = (t & 3) << 3;

  int ra0 = r0 + srow;        if (ra0 >= cnt) ra0 = cnt - 1;
  int ra1 = r0 + 64 + srow;   if (ra1 >= cnt) ra1 = cnt - 1;
  const unsigned short* aptr0 = H + (size_t)(off + ra0) * MDIM + scol;
  const unsigned short* aptr1 = H + (size_t)(off + ra1) * MDIM + scol;
  const unsigned short* bptr0 = w2t + ((size_t)e * DDIM + (ct << 7) + srow) * MDIM + scol;
  const unsigned short* bptr1 = bptr0 + (size_t)64 * MDIM;

  unsigned short* As0 = &As[srow * 32 + scol];
  unsigned short* As1 = &As[(srow + 64) * 32 + scol];
  unsigned short* Bs0 = &Bs[srow * 32 + scol];
  unsigned short* Bs1 = &Bs[(srow + 64) * 32 + scol];

  int lane = t & 63;
  int wv = t >> 6;
  int wr = (wv >> 1) << 6;
  int wc = (wv & 1) << 6;
  int lm = lane & 15;
  int lq = lane >> 4;

  const unsigned short* Ar[4];
  const unsigned short* Br[4];
  #pragma unroll
  for (int i = 0; i < 4; i++){
    Ar[i] = &As[(wr + i * 16 + lm) * 32 + lq * 8];
    Br[i] = &Bs[(wc + i * 16 + lm) * 32 + lq * 8];
  }

  floatx4 acc[4][4] = {};
  for (int k0 = 0; k0 < MDIM; k0 += 32){
    *(short8*)As0 = *(const short8*)(aptr0 + k0);
    *(short8*)As1 = *(const short8*)(aptr1 + k0);
    *(short8*)Bs0 = *(const short8*)(bptr0 + k0);
    *(short8*)Bs1 = *(const short8*)(bptr1 + k0);
    __syncthreads();
    short8 af[4], bf[4];
    #pragma unroll
    for (int i = 0; i < 4; i++) af[i] = *(const short8*)Ar[i];
    #pragma unroll
    for (int j = 0; j < 4; j++) bf[j] = *(const short8*)Br[j];
    #pragma unroll
    for (int i = 0; i < 4; i++)
      #pragma unroll
      for (int j = 0; j < 4; j++)
        acc[i][j] = __builtin_amdgcn_mfma_f32_16x16x32_bf16(af[i], bf[j], acc[i][j], 0, 0, 0);
    __syncthreads();
  }

  const float* bias = b2 + e * DDIM + (ct << 7);
  #pragma unroll
  for (int i = 0; i < 4; i++){
    int rbase = wr + i * 16 + lq * 4;
    #pragma unroll
    for (int j = 0; j < 4; j++){
      int cc = wc + j * 16 + lm;
      float bv = bias[cc];
      #pragma unroll
      for (int r = 0; r < 4; r++){
        int row = r0 + rbase + r;
        if (row < cnt){
          int tok = btok[off + row];
          float g = bgate[off + row];
          atomicAdd(&y[(size_t)tok * DDIM + (ct << 7) + cc], g * (acc[i][j][r] + bv));
        }
      }
    }
  }
}

// ---------------- launch ----------------

extern "C" void kernel_launch(void* const* d_in, const int* in_sizes, int n_in,
                              void* d_out, int out_size, void* d_ws, size_t ws_size,
                              hipStream_t stream){
  const float* x  = (const float*)d_in[0];
  const float* wg = (const float*)d_in[1];
  const float* W1 = (const float*)d_in[2];
  const float* b1 = (const float*)d_in[3];
  const float* W2 = (const float*)d_in[4];
  const float* b2 = (const float*)d_in[5];
  float* y = (float*)d_out;

  char* ws = (char*)d_ws;
  size_t o = 0;
  auto alloc = [&](size_t bytes)->char*{
    char* p = ws + o;
    o += (bytes + 255) & ~(size_t)255;
    return p;
  };
  unsigned short* xb   = (unsigned short*)alloc((size_t)NTOK * DDIM * 2);
  unsigned short* w1t  = (unsigned short*)alloc((size_t)NEXP * MDIM * DDIM * 2);
  unsigned short* w2t  = (unsigned short*)alloc((size_t)NEXP * DDIM * MDIM * 2);
  unsigned short* H    = (unsigned short*)alloc((size_t)NTOK * 2 * MDIM * 2);
  int*   btok    = (int*)  alloc((size_t)NTOK * 2 * 4);
  float* bgate   = (float*)alloc((size_t)NTOK * 2 * 4);
  int*   tok_e   = (int*)  alloc((size_t)NTOK * 2 * 4);
  float* tok_g   = (float*)alloc((size_t)NTOK * 2 * 4);
  int*   counts  = (int*)  alloc(64);
  float* imp     = (float*)alloc(64);
  int*   offsets = (int*)  alloc(64);
  int*   cursor  = (int*)  alloc(64);

  hipLaunchKernelGGL(init_small_kernel, dim3(1), dim3(64), 0, stream, counts, imp);
  hipLaunchKernelGGL(transpose_conv_kernel, dim3(MDIM / 32, DDIM / 32, NEXP), dim3(32, 8), 0, stream,
                     W1, w1t, DDIM, MDIM);
  hipLaunchKernelGGL(transpose_conv_kernel, dim3(DDIM / 32, MDIM / 32, NEXP), dim3(32, 8), 0, stream,
                     W2, w2t, MDIM, DDIM);
  hipLaunchKernelGGL(gating_kernel, dim3(NTOK / 64), dim3(256), 0, stream,
                     x, wg, xb, tok_e, tok_g, counts, imp);
  hipLaunchKernelGGL(loss_scan_kernel, dim3(1), dim3(1), 0, stream,
                     counts, imp, offsets, cursor, y + (size_t)NTOK * DDIM);
  hipLaunchKernelGGL(scatter_kernel, dim3(NTOK / 256), dim3(256), 0, stream,
                     tok_e, tok_g, cursor, btok, bgate);
  hipLaunchKernelGGL(zero_y_kernel, dim3(2048), dim3(256), 0, stream,
                     y, NTOK * DDIM / 4);
  hipLaunchKernelGGL(gemm1_kernel, dim3(NEXP * 8 * 128), dim3(256), 0, stream,
                     xb, w1t, b1, offsets, btok, H);
  hipLaunchKernelGGL(gemm2_kernel, dim3(NEXP * 4 * 128), dim3(256), 0, stream,
                     H, w2t, b2, offsets, btok, bgate, y);
}

// Round 3
// 377.253 us; speedup vs baseline: 2.4762x; 1.0757x over previous
//
#include <hip/hip_runtime.h>
#include <math.h>

#define NTOK 16384
#define DDIM 512
#define MDIM 1024
#define NEXP 8
#define LDSW 40   // LDS row stride in shorts: 80B = 20 banks, 16B-aligned, conflict-free-ish

typedef __attribute__((ext_vector_type(8))) short short8;
typedef __attribute__((ext_vector_type(4))) float floatx4;

__device__ inline unsigned short f2bf(float f){
  union { float f; unsigned int u; } v; v.f = f;
  unsigned int u = v.u;
  u += ((u >> 16) & 1u) + 0x7fffu;   // round-to-nearest-even
  return (unsigned short)(u >> 16);
}

__device__ inline float bf2f(unsigned short s){
  union { unsigned int u; float f; } v;
  v.u = ((unsigned int)s) << 16;
  return v.f;
}

__device__ inline float gelu_exact(float x){
  return 0.5f * x * (1.0f + erff(x * 0.70710678118654752440f));
}

// ---------------- small setup kernels ----------------

__global__ void init_small_kernel(int* counts, float* imp){
  int t = threadIdx.x;
  if (t < NEXP){ counts[t] = 0; imp[t] = 0.0f; }
}

// out[e][c][r] = bf16(in[e][r][c]); per-expert matrix is R x C
__global__ void transpose_conv_kernel(const float* __restrict__ in,
                                      unsigned short* __restrict__ out,
                                      int R, int C){
  __shared__ float tile[32][33];
  int e  = blockIdx.z;
  int c0 = blockIdx.x << 5;
  int r0 = blockIdx.y << 5;
  const float* src = in + (size_t)e * R * C;
  unsigned short* dst = out + (size_t)e * R * C;
  int tc = threadIdx.x;   // 0..31
  int tr = threadIdx.y;   // 0..7
  #pragma unroll
  for (int i = 0; i < 32; i += 8)
    tile[tr + i][tc] = src[(size_t)(r0 + tr + i) * C + c0 + tc];
  __syncthreads();
  #pragma unroll
  for (int i = 0; i < 32; i += 8)
    dst[(size_t)(c0 + tr + i) * R + r0 + tc] = f2bf(tile[tc][tr + i]);
}

// ---------------- fused gating + x->bf16 conversion ----------------

__global__ __launch_bounds__(256)
void gating_kernel(const float* __restrict__ x,
                   const float* __restrict__ wg,
                   unsigned short* __restrict__ xb,
                   int* __restrict__ tok_e, float* __restrict__ tok_g,
                   int* __restrict__ counts, float* __restrict__ imp){
  __shared__ int   lcnt[NEXP];
  __shared__ float limp[NEXP];
  int t = threadIdx.x;
  if (t < NEXP){ lcnt[t] = 0; limp[t] = 0.0f; }
  __syncthreads();

  int wave = t >> 6;
  int lane = t & 63;

  for (int it = 0; it < 16; it++){
    int n = blockIdx.x * 64 + it * 4 + wave;

    const float4* xp = (const float4*)(x + (size_t)n * DDIM + lane * 8);
    float4 a = xp[0], b = xp[1];
    float xv[8] = {a.x, a.y, a.z, a.w, b.x, b.y, b.z, b.w};

    short8 xo;
    #pragma unroll
    for (int j = 0; j < 8; j++) xo[j] = (short)f2bf(xv[j]);
    *(short8*)(xb + (size_t)n * DDIM + lane * 8) = xo;

    double acc[NEXP];
    #pragma unroll
    for (int e = 0; e < NEXP; e++) acc[e] = 0.0;
    #pragma unroll
    for (int j = 0; j < 8; j++){
      const float* wr = wg + (size_t)(lane * 8 + j) * NEXP;
      #pragma unroll
      for (int e = 0; e < NEXP; e++) acc[e] += (double)xv[j] * (double)wr[e];
    }
    #pragma unroll
    for (int off = 32; off >= 1; off >>= 1){
      #pragma unroll
      for (int e = 0; e < NEXP; e++) acc[e] += __shfl_xor(acc[e], off);
    }
    if (lane == 0){
      int i0 = -1, i1 = -1;
      double l0 = -1e300, l1 = -1e300;
      #pragma unroll
      for (int e = 0; e < NEXP; e++){
        double v = acc[e];
        if (v > l0){ l1 = l0; i1 = i0; l0 = v; i0 = e; }
        else if (v > l1){ l1 = v; i1 = e; }
      }
      float ex = expf((float)(l1 - l0));
      float g0 = 1.0f / (1.0f + ex);
      float g1 = ex / (1.0f + ex);
      tok_e[n * 2]     = i0; tok_e[n * 2 + 1] = i1;
      tok_g[n * 2]     = g0; tok_g[n * 2 + 1] = g1;
      atomicAdd(&lcnt[i0], 1); atomicAdd(&lcnt[i1], 1);
      atomicAdd(&limp[i0], g0); atomicAdd(&limp[i1], g1);
    }
  }
  __syncthreads();
  if (t < NEXP){
    atomicAdd(&counts[t], lcnt[t]);
    atomicAdd(&imp[t], limp[t]);
  }
}

__global__ void loss_scan_kernel(const int* __restrict__ counts,
                                 const float* __restrict__ imp,
                                 int* __restrict__ offsets, int* __restrict__ cursor,
                                 float* __restrict__ out_loss){
  int off = 0;
  double si = 0, si2 = 0, sl = 0, sl2 = 0;
  for (int e = 0; e < NEXP; e++){
    offsets[e] = off; cursor[e] = off; off += counts[e];
    double im = (double)imp[e];
    double ld = (double)counts[e];
    si += im; si2 += im * im;
    sl += ld; sl2 += ld * ld;
  }
  offsets[NEXP] = off;
  double mi = si / 8.0, ml = sl / 8.0;
  double vi = (si2 - 8.0 * mi * mi) / 7.0;
  double vl = (sl2 - 8.0 * ml * ml) / 7.0;
  double loss = 0.01 * (vi / (mi * mi + 1e-10) + vl / (ml * ml + 1e-10));
  *out_loss = (float)loss;
}

// hierarchical scatter: LDS histogram -> 8 global atomics per block -> ranked write
// also records the inverse map slot_of[n][k] for the combine pass
__global__ __launch_bounds__(256)
void scatter_kernel(const int* __restrict__ tok_e,
                    int* __restrict__ cursor,
                    int* __restrict__ btok, int* __restrict__ slot_of){
  __shared__ int lcnt[NEXP];
  __shared__ int lbase[NEXP];
  int t = threadIdx.x;
  if (t < NEXP) lcnt[t] = 0;
  __syncthreads();

  int n = blockIdx.x * 256 + t;
  int e0 = tok_e[n * 2], e1 = tok_e[n * 2 + 1];
  int r0 = atomicAdd(&lcnt[e0], 1);
  int r1 = atomicAdd(&lcnt[e1], 1);
  __syncthreads();
  if (t < NEXP) lbase[t] = atomicAdd(&cursor[t], lcnt[t]);
  __syncthreads();
  int s0 = lbase[e0] + r0;
  int s1 = lbase[e1] + r1;
  btok[s0] = n;
  btok[s1] = n;
  slot_of[n * 2]     = s0;
  slot_of[n * 2 + 1] = s1;
}

// ---------------- expert GEMMs: 128x128 tile, BK=32, mfma 16x16x32 bf16 ----------------

__global__ __launch_bounds__(256)
void gemm1_kernel(const unsigned short* __restrict__ xb,
                  const unsigned short* __restrict__ w1t,   // [E][M][D]
                  const float* __restrict__ b1,             // [E][M]
                  const int* __restrict__ offsets,
                  const int* __restrict__ btok,
                  unsigned short* __restrict__ H){          // [slot][M]
  int blk = blockIdx.x;
  int e  = blk >> 10;          // 8 col-tiles * 128 row-tiles
  int ct = (blk >> 7) & 7;
  int rt = blk & 127;
  int off = offsets[e];
  int cnt = offsets[e + 1] - off;
  int r0 = rt << 7;
  if (r0 >= cnt) return;

  __shared__ unsigned short As[128 * LDSW];
  __shared__ unsigned short Bs[128 * LDSW];

  int t = threadIdx.x;
  int srow = t >> 2;           // 0..63
  int scol = (t & 3) << 3;     // 0,8,16,24

  int ra0 = r0 + srow;        if (ra0 >= cnt) ra0 = cnt - 1;
  int ra1 = r0 + 64 + srow;   if (ra1 >= cnt) ra1 = cnt - 1;
  const unsigned short* aptr0 = xb + (size_t)btok[off + ra0] * DDIM + scol;
  const unsigned short* aptr1 = xb + (size_t)btok[off + ra1] * DDIM + scol;
  const unsigned short* bptr0 = w1t + ((size_t)e * MDIM + (ct << 7) + srow) * DDIM + scol;
  const unsigned short* bptr1 = bptr0 + (size_t)64 * DDIM;

  unsigned short* As0 = &As[srow * LDSW + scol];
  unsigned short* As1 = &As[(srow + 64) * LDSW + scol];
  unsigned short* Bs0 = &Bs[srow * LDSW + scol];
  unsigned short* Bs1 = &Bs[(srow + 64) * LDSW + scol];

  int lane = t & 63;
  int wv = t >> 6;
  int wr = (wv >> 1) << 6;
  int wc = (wv & 1) << 6;
  int lm = lane & 15;
  int lq = lane >> 4;

  const unsigned short* Ar[4];
  const unsigned short* Br[4];
  #pragma unroll
  for (int i = 0; i < 4; i++){
    Ar[i] = &As[(wr + i * 16 + lm) * LDSW + lq * 8];
    Br[i] = &Bs[(wc + i * 16 + lm) * LDSW + lq * 8];
  }

  floatx4 acc[4][4] = {};
  for (int k0 = 0; k0 < DDIM; k0 += 32){
    *(short8*)As0 = *(const short8*)(aptr0 + k0);
    *(short8*)As1 = *(const short8*)(aptr1 + k0);
    *(short8*)Bs0 = *(const short8*)(bptr0 + k0);
    *(short8*)Bs1 = *(const short8*)(bptr1 + k0);
    __syncthreads();
    short8 af[4], bf[4];
    #pragma unroll
    for (int i = 0; i < 4; i++) af[i] = *(const short8*)Ar[i];
    #pragma unroll
    for (int j = 0; j < 4; j++) bf[j] = *(const short8*)Br[j];
    #pragma unroll
    for (int i = 0; i < 4; i++)
      #pragma unroll
      for (int j = 0; j < 4; j++)
        acc[i][j] = __builtin_amdgcn_mfma_f32_16x16x32_bf16(af[i], bf[j], acc[i][j], 0, 0, 0);
    __syncthreads();
  }

  const float* bias = b1 + e * MDIM + (ct << 7);
  #pragma unroll
  for (int i = 0; i < 4; i++){
    int rbase = wr + i * 16 + lq * 4;
    #pragma unroll
    for (int j = 0; j < 4; j++){
      int cc = wc + j * 16 + lm;
      float bv = bias[cc];
      #pragma unroll
      for (int r = 0; r < 4; r++){
        int row = r0 + rbase + r;
        if (row < cnt){
          float v = acc[i][j][r] + bv;
          H[(size_t)(off + row) * MDIM + (ct << 7) + cc] = f2bf(gelu_exact(v));
        }
      }
    }
  }
}

__global__ __launch_bounds__(256)
void gemm2_kernel(const unsigned short* __restrict__ H,    // [slot][M]
                  const unsigned short* __restrict__ w2t,  // [E][D][M]
                  const float* __restrict__ b2,            // [E][D]
                  const int* __restrict__ offsets,
                  unsigned short* __restrict__ O){         // [slot][D] bf16
  int blk = blockIdx.x;
  int e  = blk >> 9;           // 4 col-tiles * 128 row-tiles
  int ct = (blk >> 7) & 3;
  int rt = blk & 127;
  int off = offsets[e];
  int cnt = offsets[e + 1] - off;
  int r0 = rt << 7;
  if (r0 >= cnt) return;

  __shared__ unsigned short As[128 * LDSW];
  __shared__ unsigned short Bs[128 * LDSW];

  int t = threadIdx.x;
  int srow = t >> 2;
  int scol = (t & 3) << 3;

  int ra0 = r0 + srow;        if (ra0 >= cnt) ra0 = cnt - 1;
  int ra1 = r0 + 64 + srow;   if (ra1 >= cnt) ra1 = cnt - 1;
  const unsigned short* aptr0 = H + (size_t)(off + ra0) * MDIM + scol;
  const unsigned short* aptr1 = H + (size_t)(off + ra1) * MDIM + scol;
  const unsigned short* bptr0 = w2t + ((size_t)e * DDIM + (ct << 7) + srow) * MDIM + scol;
  const unsigned short* bptr1 = bptr0 + (size_t)64 * MDIM;

  unsigned short* As0 = &As[srow * LDSW + scol];
  unsigned short* As1 = &As[(srow + 64) * LDSW + scol];
  unsigned short* Bs0 = &Bs[srow * LDSW + scol];
  unsigned short* Bs1 = &Bs[(srow + 64) * LDSW + scol];

  int lane = t & 63;
  int wv = t >> 6;
  int wr = (wv >> 1) << 6;
  int wc = (wv & 1) << 6;
  int lm = lane & 15;
  int lq = lane >> 4;

  const unsigned short* Ar[4];
  const unsigned short* Br[4];
  #pragma unroll
  for (int i = 0; i < 4; i++){
    Ar[i] = &As[(wr + i * 16 + lm) * LDSW + lq * 8];
    Br[i] = &Bs[(wc + i * 16 + lm) * LDSW + lq * 8];
  }

  floatx4 acc[4][4] = {};
  for (int k0 = 0; k0 < MDIM; k0 += 32){
    *(short8*)As0 = *(const short8*)(aptr0 + k0);
    *(short8*)As1 = *(const short8*)(aptr1 + k0);
    *(short8*)Bs0 = *(const short8*)(bptr0 + k0);
    *(short8*)Bs1 = *(const short8*)(bptr1 + k0);
    __syncthreads();
    short8 af[4], bf[4];
    #pragma unroll
    for (int i = 0; i < 4; i++) af[i] = *(const short8*)Ar[i];
    #pragma unroll
    for (int j = 0; j < 4; j++) bf[j] = *(const short8*)Br[j];
    #pragma unroll
    for (int i = 0; i < 4; i++)
      #pragma unroll
      for (int j = 0; j < 4; j++)
        acc[i][j] = __builtin_amdgcn_mfma_f32_16x16x32_bf16(af[i], bf[j], acc[i][j], 0, 0, 0);
    __syncthreads();
  }

  const float* bias = b2 + e * DDIM + (ct << 7);
  #pragma unroll
  for (int i = 0; i < 4; i++){
    int rbase = wr + i * 16 + lq * 4;
    #pragma unroll
    for (int j = 0; j < 4; j++){
      int cc = wc + j * 16 + lm;
      float bv = bias[cc];
      #pragma unroll
      for (int r = 0; r < 4; r++){
        int row = r0 + rbase + r;
        if (row < cnt)
          O[(size_t)(off + row) * DDIM + (ct << 7) + cc] = f2bf(acc[i][j][r] + bv);
      }
    }
  }
}

// ---------------- gate-weighted combine: y[n] = g0*O[s0] + g1*O[s1] ----------------

__global__ __launch_bounds__(256)
void combine_kernel(const unsigned short* __restrict__ O,
                    const float* __restrict__ tok_g,
                    const int* __restrict__ slot_of,
                    float* __restrict__ y){
  int wave = threadIdx.x >> 6;
  int lane = threadIdx.x & 63;
  int n = blockIdx.x * 4 + wave;
  int s0 = slot_of[n * 2], s1 = slot_of[n * 2 + 1];
  float g0 = tok_g[n * 2], g1 = tok_g[n * 2 + 1];
  short8 a = *(const short8*)(O + (size_t)s0 * DDIM + lane * 8);
  short8 b = *(const short8*)(O + (size_t)s1 * DDIM + lane * 8);
  float4 o0, o1;
  float* po0 = (float*)&o0;
  float* po1 = (float*)&o1;
  #pragma unroll
  for (int j = 0; j < 4; j++){
    po0[j] = g0 * bf2f((unsigned short)a[j]) + g1 * bf2f((unsigned short)b[j]);
    po1[j] = g0 * bf2f((unsigned short)a[j + 4]) + g1 * bf2f((unsigned short)b[j + 4]);
  }
  float4* yp = (float4*)(y + (size_t)n * DDIM + lane * 8);
  yp[0] = o0;
  yp[1] = o1;
}

// ---------------- launch ----------------

extern "C" void kernel_launch(void* const* d_in, const int* in_sizes, int n_in,
                              void* d_out, int out_size, void* d_ws, size_t ws_size,
                              hipStream_t stream){
  const float* x  = (const float*)d_in[0];
  const float* wg = (const float*)d_in[1];
  const float* W1 = (const float*)d_in[2];
  const float* b1 = (const float*)d_in[3];
  const float* W2 = (const float*)d_in[4];
  const float* b2 = (const float*)d_in[5];
  float* y = (float*)d_out;

  char* ws = (char*)d_ws;
  size_t o = 0;
  auto alloc = [&](size_t bytes)->char*{
    char* p = ws + o;
    o += (bytes + 255) & ~(size_t)255;
    return p;
  };
  unsigned short* xb   = (unsigned short*)alloc((size_t)NTOK * DDIM * 2);
  unsigned short* w1t  = (unsigned short*)alloc((size_t)NEXP * MDIM * DDIM * 2);
  unsigned short* w2t  = (unsigned short*)alloc((size_t)NEXP * DDIM * MDIM * 2);
  unsigned short* H    = (unsigned short*)alloc((size_t)NTOK * 2 * MDIM * 2);
  unsigned short* O    = (unsigned short*)alloc((size_t)NTOK * 2 * DDIM * 2);
  int*   btok    = (int*)  alloc((size_t)NTOK * 2 * 4);
  int*   slot_of = (int*)  alloc((size_t)NTOK * 2 * 4);
  int*   tok_e   = (int*)  alloc((size_t)NTOK * 2 * 4);
  float* tok_g   = (float*)alloc((size_t)NTOK * 2 * 4);
  int*   counts  = (int*)  alloc(64);
  float* imp     = (float*)alloc(64);
  int*   offsets = (int*)  alloc(64);
  int*   cursor  = (int*)  alloc(64);

  hipLaunchKernelGGL(init_small_kernel, dim3(1), dim3(64), 0, stream, counts, imp);
  hipLaunchKernelGGL(transpose_conv_kernel, dim3(MDIM / 32, DDIM / 32, NEXP), dim3(32, 8), 0, stream,
                     W1, w1t, DDIM, MDIM);
  hipLaunchKernelGGL(transpose_conv_kernel, dim3(DDIM / 32, MDIM / 32, NEXP), dim3(32, 8), 0, stream,
                     W2, w2t, MDIM, DDIM);
  hipLaunchKernelGGL(gating_kernel, dim3(NTOK / 64), dim3(256), 0, stream,
                     x, wg, xb, tok_e, tok_g, counts, imp);
  hipLaunchKernelGGL(loss_scan_kernel, dim3(1), dim3(1), 0, stream,
                     counts, imp, offsets, cursor, y + (size_t)NTOK * DDIM);
  hipLaunchKernelGGL(scatter_kernel, dim3(NTOK / 256), dim3(256), 0, stream,
                     tok_e, cursor, btok, slot_of);
  hipLaunchKernelGGL(gemm1_kernel, dim3(NEXP * 8 * 128), dim3(256), 0, stream,
                     xb, w1t, b1, offsets, btok, H);
  hipLaunchKernelGGL(gemm2_kernel, dim3(NEXP * 4 * 128), dim3(256), 0, stream,
                     H, w2t, b2, offsets, O);
  hipLaunchKernelGGL(combine_kernel, dim3(NTOK / 4), dim3(256), 0, stream,
                     O, tok_g, slot_of, y);
}

// Round 4
// 308.592 us; speedup vs baseline: 3.0271x; 1.2225x over previous
//
#include <hip/hip_runtime.h>
#include <math.h>

#define NTOK 16384
#define DDIM 512
#define MDIM 1024
#define NEXP 8
#define LDSW 32      // MUST be 32: global_load_lds needs byte offset == lane*16
#define TMAX 264     // max row-tiles across experts: 256 + 8 partial

typedef __attribute__((ext_vector_type(8))) short short8;
typedef __attribute__((ext_vector_type(4))) float floatx4;

__device__ inline unsigned short f2bf(float f){
  union { float f; unsigned int u; } v; v.f = f;
  unsigned int u = v.u;
  u += ((u >> 16) & 1u) + 0x7fffu;   // round-to-nearest-even
  return (unsigned short)(u >> 16);
}

__device__ inline float bf2f(unsigned short s){
  union { unsigned int u; float f; } v;
  v.u = ((unsigned int)s) << 16;
  return v.f;
}

// branch-free erf-based gelu, A&S 7.1.26 (|erf err| <= 1.5e-7)
__device__ inline float gelu_fast(float x){
  float u = x * 0.70710678118654752f;
  float a = fabsf(u);
  float t = __builtin_amdgcn_rcpf(fmaf(0.3275911f, a, 1.0f));
  float p = fmaf(1.061405429f, t, -1.453152027f);
  p = fmaf(p, t, 1.421413741f);
  p = fmaf(p, t, -0.284496736f);
  p = fmaf(p, t, 0.254829592f);
  p = p * t;
  float e = __expf(-u * u);
  float erfa = fmaf(-p, e, 1.0f);         // erf(|u|)
  float erfu = copysignf(erfa, u);
  return 0.5f * x * (1.0f + erfu);
}

// async global -> LDS, 16 bytes per lane; lds base must be wave-uniform
__device__ __forceinline__ void gload16(const unsigned short* g, unsigned short* l){
  __builtin_amdgcn_global_load_lds(
      (const __attribute__((address_space(1))) void*)g,
      (__attribute__((address_space(3))) void*)l,
      16, 0, 0);
}

// ---------------- small setup kernels ----------------

__global__ void init_small_kernel(int* counts, float* imp){
  int t = threadIdx.x;
  if (t < NEXP){ counts[t] = 0; imp[t] = 0.0f; }
}

// out[e][c][r] = bf16(in[e][r][c]); per-expert matrix is R x C
__global__ void transpose_conv_kernel(const float* __restrict__ in,
                                      unsigned short* __restrict__ out,
                                      int R, int C){
  __shared__ float tile[32][33];
  int e  = blockIdx.z;
  int c0 = blockIdx.x << 5;
  int r0 = blockIdx.y << 5;
  const float* src = in + (size_t)e * R * C;
  unsigned short* dst = out + (size_t)e * R * C;
  int tc = threadIdx.x;   // 0..31
  int tr = threadIdx.y;   // 0..7
  #pragma unroll
  for (int i = 0; i < 32; i += 8)
    tile[tr + i][tc] = src[(size_t)(r0 + tr + i) * C + c0 + tc];
  __syncthreads();
  #pragma unroll
  for (int i = 0; i < 32; i += 8)
    dst[(size_t)(c0 + tr + i) * R + r0 + tc] = f2bf(tile[tc][tr + i]);
}

// ---------------- fused gating + x->bf16 conversion ----------------

__global__ __launch_bounds__(256)
void gating_kernel(const float* __restrict__ x,
                   const float* __restrict__ wg,
                   unsigned short* __restrict__ xb,
                   int* __restrict__ tok_e, float* __restrict__ tok_g,
                   int* __restrict__ counts, float* __restrict__ imp){
  __shared__ int   lcnt[NEXP];
  __shared__ float limp[NEXP];
  int t = threadIdx.x;
  if (t < NEXP){ lcnt[t] = 0; limp[t] = 0.0f; }
  __syncthreads();

  int wave = t >> 6;
  int lane = t & 63;

  for (int it = 0; it < 16; it++){
    int n = blockIdx.x * 64 + it * 4 + wave;

    const float4* xp = (const float4*)(x + (size_t)n * DDIM + lane * 8);
    float4 a = xp[0], b = xp[1];
    float xv[8] = {a.x, a.y, a.z, a.w, b.x, b.y, b.z, b.w};

    short8 xo;
    #pragma unroll
    for (int j = 0; j < 8; j++) xo[j] = (short)f2bf(xv[j]);
    *(short8*)(xb + (size_t)n * DDIM + lane * 8) = xo;

    double acc[NEXP];
    #pragma unroll
    for (int e = 0; e < NEXP; e++) acc[e] = 0.0;
    #pragma unroll
    for (int j = 0; j < 8; j++){
      const float* wr = wg + (size_t)(lane * 8 + j) * NEXP;
      #pragma unroll
      for (int e = 0; e < NEXP; e++) acc[e] += (double)xv[j] * (double)wr[e];
    }
    #pragma unroll
    for (int off = 32; off >= 1; off >>= 1){
      #pragma unroll
      for (int e = 0; e < NEXP; e++) acc[e] += __shfl_xor(acc[e], off);
    }
    if (lane == 0){
      int i0 = -1, i1 = -1;
      double l0 = -1e300, l1 = -1e300;
      #pragma unroll
      for (int e = 0; e < NEXP; e++){
        double v = acc[e];
        if (v > l0){ l1 = l0; i1 = i0; l0 = v; i0 = e; }
        else if (v > l1){ l1 = v; i1 = e; }
      }
      float ex = expf((float)(l1 - l0));
      float g0 = 1.0f / (1.0f + ex);
      float g1 = ex / (1.0f + ex);
      tok_e[n * 2]     = i0; tok_e[n * 2 + 1] = i1;
      tok_g[n * 2]     = g0; tok_g[n * 2 + 1] = g1;
      atomicAdd(&lcnt[i0], 1); atomicAdd(&lcnt[i1], 1);
      atomicAdd(&limp[i0], g0); atomicAdd(&limp[i1], g1);
    }
  }
  __syncthreads();
  if (t < NEXP){
    atomicAdd(&counts[t], lcnt[t]);
    atomicAdd(&imp[t], limp[t]);
  }
}

__global__ void loss_scan_kernel(const int* __restrict__ counts,
                                 const float* __restrict__ imp,
                                 int* __restrict__ offsets, int* __restrict__ cursor,
                                 int* __restrict__ tile_pre,
                                 float* __restrict__ out_loss){
  int off = 0, tp = 0;
  double si = 0, si2 = 0, sl = 0, sl2 = 0;
  for (int e = 0; e < NEXP; e++){
    offsets[e] = off; cursor[e] = off;
    tile_pre[e] = tp;
    tp += (counts[e] + 127) >> 7;
    off += counts[e];
    double im = (double)imp[e];
    double ld = (double)counts[e];
    si += im; si2 += im * im;
    sl += ld; sl2 += ld * ld;
  }
  offsets[NEXP] = off;
  tile_pre[NEXP] = tp;
  double mi = si / 8.0, ml = sl / 8.0;
  double vi = (si2 - 8.0 * mi * mi) / 7.0;
  double vl = (sl2 - 8.0 * ml * ml) / 7.0;
  double loss = 0.01 * (vi / (mi * mi + 1e-10) + vl / (ml * ml + 1e-10));
  *out_loss = (float)loss;
}

// hierarchical scatter: LDS histogram -> 8 global atomics per block -> ranked write
__global__ __launch_bounds__(256)
void scatter_kernel(const int* __restrict__ tok_e,
                    int* __restrict__ cursor,
                    int* __restrict__ btok, int* __restrict__ slot_of){
  __shared__ int lcnt[NEXP];
  __shared__ int lbase[NEXP];
  int t = threadIdx.x;
  if (t < NEXP) lcnt[t] = 0;
  __syncthreads();

  int n = blockIdx.x * 256 + t;
  int e0 = tok_e[n * 2], e1 = tok_e[n * 2 + 1];
  int r0 = atomicAdd(&lcnt[e0], 1);
  int r1 = atomicAdd(&lcnt[e1], 1);
  __syncthreads();
  if (t < NEXP) lbase[t] = atomicAdd(&cursor[t], lcnt[t]);
  __syncthreads();
  int s0 = lbase[e0] + r0;
  int s1 = lbase[e1] + r1;
  btok[s0] = n;
  btok[s1] = n;
  slot_of[n * 2]     = s0;
  slot_of[n * 2 + 1] = s1;
}

// ---------------- expert GEMMs: 128x128 tile, BK=32, mfma 16x16x32 bf16 ----------------
// global_load_lds (16B/lane) staging; LDS layout = lane*16 bytes, stride 32 shorts.

__global__ __launch_bounds__(256)
void gemm1_kernel(const unsigned short* __restrict__ xb,
                  const unsigned short* __restrict__ w1t,   // [E][M][D]
                  const float* __restrict__ b1,             // [E][M]
                  const int* __restrict__ offsets,
                  const int* __restrict__ tile_pre,
                  const int* __restrict__ btok,
                  unsigned short* __restrict__ H){          // [slot][M]
  int ct = blockIdx.x / TMAX;          // 0..7
  int tt = blockIdx.x % TMAX;
  if (tt >= tile_pre[NEXP]) return;
  int e = 0;
  while (tt >= tile_pre[e + 1]) e++;
  int rt = tt - tile_pre[e];
  int off = offsets[e];
  int cnt = offsets[e + 1] - off;
  int r0 = rt << 7;

  __shared__ unsigned short As[128 * LDSW];
  __shared__ unsigned short Bs[128 * LDSW];

  int t = threadIdx.x;
  int srow = t >> 2;           // 0..63
  int scol = (t & 3) << 3;     // 0,8,16,24
  int w = t >> 6;

  int ra0 = r0 + srow;        if (ra0 >= cnt) ra0 = cnt - 1;
  int ra1 = r0 + 64 + srow;   if (ra1 >= cnt) ra1 = cnt - 1;
  const unsigned short* aptr0 = xb + (size_t)btok[off + ra0] * DDIM + scol;
  const unsigned short* aptr1 = xb + (size_t)btok[off + ra1] * DDIM + scol;
  const unsigned short* bptr0 = w1t + ((size_t)e * MDIM + (ct << 7) + srow) * DDIM + scol;
  const unsigned short* bptr1 = bptr0 + (size_t)64 * DDIM;

  // wave-uniform LDS bases: lane l lands at base + l*16 bytes
  unsigned short* As0 = As + w * 512;             // bytes w*1024
  unsigned short* As1 = As + 2048 + w * 512;      // second 64 rows
  unsigned short* Bs0 = Bs + w * 512;
  unsigned short* Bs1 = Bs + 2048 + w * 512;

  int lane = t & 63;
  int wr = (w >> 1) << 6;
  int wc = (w & 1) << 6;
  int lm = lane & 15;
  int lq = lane >> 4;

  const unsigned short* Ar[4];
  const unsigned short* Br[4];
  #pragma unroll
  for (int i = 0; i < 4; i++){
    Ar[i] = &As[(wr + i * 16 + lm) * LDSW + lq * 8];
    Br[i] = &Bs[(wc + i * 16 + lm) * LDSW + lq * 8];
  }

  floatx4 acc[4][4] = {};
  for (int k0 = 0; k0 < DDIM; k0 += 32){
    gload16(aptr0 + k0, As0);
    gload16(aptr1 + k0, As1);
    gload16(bptr0 + k0, Bs0);
    gload16(bptr1 + k0, Bs1);
    __syncthreads();
    short8 af[4], bf[4];
    #pragma unroll
    for (int i = 0; i < 4; i++) af[i] = *(const short8*)Ar[i];
    #pragma unroll
    for (int j = 0; j < 4; j++) bf[j] = *(const short8*)Br[j];
    #pragma unroll
    for (int i = 0; i < 4; i++)
      #pragma unroll
      for (int j = 0; j < 4; j++)
        acc[i][j] = __builtin_amdgcn_mfma_f32_16x16x32_bf16(af[i], bf[j], acc[i][j], 0, 0, 0);
    __syncthreads();
  }

  const float* bias = b1 + e * MDIM + (ct << 7);
  #pragma unroll
  for (int i = 0; i < 4; i++){
    int rbase = wr + i * 16 + lq * 4;
    #pragma unroll
    for (int j = 0; j < 4; j++){
      int cc = wc + j * 16 + lm;
      float bv = bias[cc];
      #pragma unroll
      for (int r = 0; r < 4; r++){
        int row = r0 + rbase + r;
        if (row < cnt){
          float v = acc[i][j][r] + bv;
          H[(size_t)(off + row) * MDIM + (ct << 7) + cc] = f2bf(gelu_fast(v));
        }
      }
    }
  }
}

__global__ __launch_bounds__(256)
void gemm2_kernel(const unsigned short* __restrict__ H,    // [slot][M]
                  const unsigned short* __restrict__ w2t,  // [E][D][M]
                  const float* __restrict__ b2,            // [E][D]
                  const int* __restrict__ offsets,
                  const int* __restrict__ tile_pre,
                  unsigned short* __restrict__ O){         // [slot][D] bf16
  int ct = blockIdx.x / TMAX;          // 0..3
  int tt = blockIdx.x % TMAX;
  if (tt >= tile_pre[NEXP]) return;
  int e = 0;
  while (tt >= tile_pre[e + 1]) e++;
  int rt = tt - tile_pre[e];
  int off = offsets[e];
  int cnt = offsets[e + 1] - off;
  int r0 = rt << 7;

  __shared__ unsigned short As[128 * LDSW];
  __shared__ unsigned short Bs[128 * LDSW];

  int t = threadIdx.x;
  int srow = t >> 2;
  int scol = (t & 3) << 3;
  int w = t >> 6;

  int ra0 = r0 + srow;        if (ra0 >= cnt) ra0 = cnt - 1;
  int ra1 = r0 + 64 + srow;   if (ra1 >= cnt) ra1 = cnt - 1;
  const unsigned short* aptr0 = H + (size_t)(off + ra0) * MDIM + scol;
  const unsigned short* aptr1 = H + (size_t)(off + ra1) * MDIM + scol;
  const unsigned short* bptr0 = w2t + ((size_t)e * DDIM + (ct << 7) + srow) * MDIM + scol;
  const unsigned short* bptr1 = bptr0 + (size_t)64 * MDIM;

  unsigned short* As0 = As + w * 512;
  unsigned short* As1 = As + 2048 + w * 512;
  unsigned short* Bs0 = Bs + w * 512;
  unsigned short* Bs1 = Bs + 2048 + w * 512;

  int lane = t & 63;
  int wr = (w >> 1) << 6;
  int wc = (w & 1) << 6;
  int lm = lane & 15;
  int lq = lane >> 4;

  const unsigned short* Ar[4];
  const unsigned short* Br[4];
  #pragma unroll
  for (int i = 0; i < 4; i++){
    Ar[i] = &As[(wr + i * 16 + lm) * LDSW + lq * 8];
    Br[i] = &Bs[(wc + i * 16 + lm) * LDSW + lq * 8];
  }

  floatx4 acc[4][4] = {};
  for (int k0 = 0; k0 < MDIM; k0 += 32){
    gload16(aptr0 + k0, As0);
    gload16(aptr1 + k0, As1);
    gload16(bptr0 + k0, Bs0);
    gload16(bptr1 + k0, Bs1);
    __syncthreads();
    short8 af[4], bf[4];
    #pragma unroll
    for (int i = 0; i < 4; i++) af[i] = *(const short8*)Ar[i];
    #pragma unroll
    for (int j = 0; j < 4; j++) bf[j] = *(const short8*)Br[j];
    #pragma unroll
    for (int i = 0; i < 4; i++)
      #pragma unroll
      for (int j = 0; j < 4; j++)
        acc[i][j] = __builtin_amdgcn_mfma_f32_16x16x32_bf16(af[i], bf[j], acc[i][j], 0, 0, 0);
    __syncthreads();
  }

  const float* bias = b2 + e * DDIM + (ct << 7);
  #pragma unroll
  for (int i = 0; i < 4; i++){
    int rbase = wr + i * 16 + lq * 4;
    #pragma unroll
    for (int j = 0; j < 4; j++){
      int cc = wc + j * 16 + lm;
      float bv = bias[cc];
      #pragma unroll
      for (int r = 0; r < 4; r++){
        int row = r0 + rbase + r;
        if (row < cnt)
          O[(size_t)(off + row) * DDIM + (ct << 7) + cc] = f2bf(acc[i][j][r] + bv);
      }
    }
  }
}

// ---------------- gate-weighted combine: y[n] = g0*O[s0] + g1*O[s1] ----------------

__global__ __launch_bounds__(256)
void combine_kernel(const unsigned short* __restrict__ O,
                    const float* __restrict__ tok_g,
                    const int* __restrict__ slot_of,
                    float* __restrict__ y){
  int wave = threadIdx.x >> 6;
  int lane = threadIdx.x & 63;
  int n = blockIdx.x * 4 + wave;
  int s0 = slot_of[n * 2], s1 = slot_of[n * 2 + 1];
  float g0 = tok_g[n * 2], g1 = tok_g[n * 2 + 1];
  short8 a = *(const short8*)(O + (size_t)s0 * DDIM + lane * 8);
  short8 b = *(const short8*)(O + (size_t)s1 * DDIM + lane * 8);
  float4 o0, o1;
  float* po0 = (float*)&o0;
  float* po1 = (float*)&o1;
  #pragma unroll
  for (int j = 0; j < 4; j++){
    po0[j] = g0 * bf2f((unsigned short)a[j]) + g1 * bf2f((unsigned short)b[j]);
    po1[j] = g0 * bf2f((unsigned short)a[j + 4]) + g1 * bf2f((unsigned short)b[j + 4]);
  }
  float4* yp = (float4*)(y + (size_t)n * DDIM + lane * 8);
  yp[0] = o0;
  yp[1] = o1;
}

// ---------------- launch ----------------

extern "C" void kernel_launch(void* const* d_in, const int* in_sizes, int n_in,
                              void* d_out, int out_size, void* d_ws, size_t ws_size,
                              hipStream_t stream){
  const float* x  = (const float*)d_in[0];
  const float* wg = (const float*)d_in[1];
  const float* W1 = (const float*)d_in[2];
  const float* b1 = (const float*)d_in[3];
  const float* W2 = (const float*)d_in[4];
  const float* b2 = (const float*)d_in[5];
  float* y = (float*)d_out;

  char* ws = (char*)d_ws;
  size_t o = 0;
  auto alloc = [&](size_t bytes)->char*{
    char* p = ws + o;
    o += (bytes + 255) & ~(size_t)255;
    return p;
  };
  unsigned short* xb   = (unsigned short*)alloc((size_t)NTOK * DDIM * 2);
  unsigned short* w1t  = (unsigned short*)alloc((size_t)NEXP * MDIM * DDIM * 2);
  unsigned short* w2t  = (unsigned short*)alloc((size_t)NEXP * DDIM * MDIM * 2);
  unsigned short* H    = (unsigned short*)alloc((size_t)NTOK * 2 * MDIM * 2);
  unsigned short* O    = (unsigned short*)alloc((size_t)NTOK * 2 * DDIM * 2);
  int*   btok    = (int*)  alloc((size_t)NTOK * 2 * 4);
  int*   slot_of = (int*)  alloc((size_t)NTOK * 2 * 4);
  int*   tok_e   = (int*)  alloc((size_t)NTOK * 2 * 4);
  float* tok_g   = (float*)alloc((size_t)NTOK * 2 * 4);
  int*   counts  = (int*)  alloc(64);
  float* imp     = (float*)alloc(64);
  int*   offsets = (int*)  alloc(64);
  int*   cursor  = (int*)  alloc(64);
  int*   tile_pre= (int*)  alloc(64);

  hipLaunchKernelGGL(init_small_kernel, dim3(1), dim3(64), 0, stream, counts, imp);
  hipLaunchKernelGGL(transpose_conv_kernel, dim3(MDIM / 32, DDIM / 32, NEXP), dim3(32, 8), 0, stream,
                     W1, w1t, DDIM, MDIM);
  hipLaunchKernelGGL(transpose_conv_kernel, dim3(DDIM / 32, MDIM / 32, NEXP), dim3(32, 8), 0, stream,
                     W2, w2t, MDIM, DDIM);
  hipLaunchKernelGGL(gating_kernel, dim3(NTOK / 64), dim3(256), 0, stream,
                     x, wg, xb, tok_e, tok_g, counts, imp);
  hipLaunchKernelGGL(loss_scan_kernel, dim3(1), dim3(1), 0, stream,
                     counts, imp, offsets, cursor, tile_pre, y + (size_t)NTOK * DDIM);
  hipLaunchKernelGGL(scatter_kernel, dim3(NTOK / 256), dim3(256), 0, stream,
                     tok_e, cursor, btok, slot_of);
  hipLaunchKernelGGL(gemm1_kernel, dim3(TMAX * 8), dim3(256), 0, stream,
                     xb, w1t, b1, offsets, tile_pre, btok, H);
  hipLaunchKernelGGL(gemm2_kernel, dim3(TMAX * 4), dim3(256), 0, stream,
                     H, w2t, b2, offsets, tile_pre, O);
  hipLaunchKernelGGL(combine_kernel, dim3(NTOK / 4), dim3(256), 0, stream,
                     O, tok_g, slot_of, y);
}